// Round 1
// baseline (993.542 us; speedup 1.0000x reference)
//
#include <hip/hip_runtime.h>

#define NPOS 4096      // H*W
#define NCH 256        // channels
#define NHEAD 8
#define HDIM 32
#define OCH 8          // output channels per projection block
#define MT 128         // key tile for attention

__device__ __constant__ float kScale = 0.17677669529663687f;  // 1/sqrt(32)

// Y[o][n] = sum_c W[o][c] * X[c][n] (+ bias[o])
// grid: (NPOS/256, NCH/OCH), block: 256
__global__ void proj_kernel(const float* __restrict__ X,
                            const float* __restrict__ W,
                            const float* __restrict__ bias,
                            float* __restrict__ Y) {
    __shared__ float w_lds[OCH * NCH];
    const int n  = blockIdx.x * 256 + threadIdx.x;
    const int o0 = blockIdx.y * OCH;
    for (int i = threadIdx.x; i < OCH * NCH; i += 256)
        w_lds[i] = W[o0 * NCH + i];
    __syncthreads();

    float acc[OCH];
#pragma unroll
    for (int j = 0; j < OCH; ++j) acc[j] = 0.f;

#pragma unroll 4
    for (int c = 0; c < NCH; ++c) {
        float xv = X[c * NPOS + n];
#pragma unroll
        for (int j = 0; j < OCH; ++j)
            acc[j] = fmaf(w_lds[j * NCH + c], xv, acc[j]);
    }

#pragma unroll
    for (int j = 0; j < OCH; ++j) {
        float b = bias ? bias[o0 + j] : 0.f;
        Y[(o0 + j) * NPOS + n] = acc[j] + b;
    }
}

// Flash attention, f32. Q,K,V layout: [(head*32+d)][n].
// grid: (NPOS/64, NHEAD), block 256 = 64 queries x 4 key-splits.
__global__ void attn_kernel(const float* __restrict__ Q,
                            const float* __restrict__ K,
                            const float* __restrict__ V,
                            float* __restrict__ O) {
    __shared__ float k_lds[HDIM][MT];
    __shared__ float v_lds[HDIM][MT];
    const int h     = blockIdx.y;
    const int qi    = blockIdx.x * 64 + (threadIdx.x >> 2);
    const int split = threadIdx.x & 3;

    float q[HDIM], acc[HDIM], s[MT / 4];
#pragma unroll
    for (int d = 0; d < HDIM; ++d) {
        q[d]   = Q[(h * HDIM + d) * NPOS + qi] * kScale;
        acc[d] = 0.f;
    }
    float m_run = -1e30f, l_run = 0.f;

    for (int m0 = 0; m0 < NPOS; m0 += MT) {
        __syncthreads();
        for (int e = threadIdx.x; e < HDIM * MT; e += 256) {
            int d = e >> 7, mm = e & (MT - 1);
            k_lds[d][mm] = K[(h * HDIM + d) * NPOS + m0 + mm];
            v_lds[d][mm] = V[(h * HDIM + d) * NPOS + m0 + mm];
        }
        __syncthreads();

        float mt = -1e30f;
#pragma unroll
        for (int t = 0; t < MT / 4; ++t) {
            const int mm = split + t * 4;
            float sv = 0.f;
#pragma unroll
            for (int d = 0; d < HDIM; ++d)
                sv = fmaf(q[d], k_lds[d][mm], sv);
            s[t] = sv;
            mt = fmaxf(mt, sv);
        }
        const float m_new = fmaxf(m_run, mt);
        const float alpha = __expf(m_run - m_new);
        l_run *= alpha;
#pragma unroll
        for (int d = 0; d < HDIM; ++d) acc[d] *= alpha;

#pragma unroll
        for (int t = 0; t < MT / 4; ++t) {
            const int mm = split + t * 4;
            const float p = __expf(s[t] - m_new);
            l_run += p;
#pragma unroll
            for (int d = 0; d < HDIM; ++d)
                acc[d] = fmaf(p, v_lds[d][mm], acc[d]);
        }
        m_run = m_new;
    }

    // merge the 4 key-splits (lanes 4q..4q+3 hold the same query)
#pragma unroll
    for (int off = 1; off < 4; off <<= 1) {
        float m_o = __shfl_xor(m_run, off, 64);
        float l_o = __shfl_xor(l_run, off, 64);
        float m_new = fmaxf(m_run, m_o);
        float a = __expf(m_run - m_new);
        float b = __expf(m_o - m_new);
        l_run = l_run * a + l_o * b;
#pragma unroll
        for (int d = 0; d < HDIM; ++d) {
            float acc_o = __shfl_xor(acc[d], off, 64);
            acc[d] = acc[d] * a + acc_o * b;
        }
        m_run = m_new;
    }

    const float inv_l = 1.f / l_run;
#pragma unroll
    for (int d = 0; d < HDIM; ++d) {
        if ((d >> 3) == split)
            O[(h * HDIM + d) * NPOS + qi] = acc[d] * inv_l;
    }
}

extern "C" void kernel_launch(void* const* d_in, const int* in_sizes, int n_in,
                              void* d_out, int out_size, void* d_ws, size_t ws_size,
                              hipStream_t stream) {
    const float* x1 = (const float*)d_in[0];
    const float* x2 = (const float*)d_in[1];
    const float* Wq = (const float*)d_in[2];
    const float* Wk = (const float*)d_in[3];
    const float* Wv = (const float*)d_in[4];
    const float* Wp = (const float*)d_in[5];
    const float* bp = (const float*)d_in[6];
    float* out = (float*)d_out;

    float* q = (float*)d_ws;
    float* k = q + NCH * NPOS;
    float* v = k + NCH * NPOS;
    float* f = v + NCH * NPOS;

    dim3 pgrid(NPOS / 256, NCH / OCH);
    proj_kernel<<<pgrid, 256, 0, stream>>>(x1, Wq, nullptr, q);
    proj_kernel<<<pgrid, 256, 0, stream>>>(x2, Wk, nullptr, k);
    proj_kernel<<<pgrid, 256, 0, stream>>>(x2, Wv, nullptr, v);

    attn_kernel<<<dim3(NPOS / 64, NHEAD), 256, 0, stream>>>(q, k, v, f);

    proj_kernel<<<pgrid, 256, 0, stream>>>(f, Wp, bp, out);
}

// Round 2
// 131.085 us; speedup vs baseline: 7.5794x; 7.5794x over previous
//
#include <hip/hip_runtime.h>

#define NPOS 4096      // H*W
#define NCH  256       // channels
#define HD   32        // head dim
#define KB   64        // keys per attention step

typedef float f32x4 __attribute__((ext_vector_type(4)));
typedef short s16x8 __attribute__((ext_vector_type(8)));

static __device__ __forceinline__ s16x8 load8(const ushort* p) {
    return *(const s16x8*)p;
}
static __device__ __forceinline__ ushort bfbits(float x) {
    __bf16 b = (__bf16)x;
    return __builtin_bit_cast(unsigned short, b);
}
static __device__ __forceinline__ uint pk2(float a, float b) {
    return (uint)bfbits(a) | ((uint)bfbits(b) << 16);
}
static __device__ __forceinline__ f32x4 max4(f32x4 a, f32x4 b) {
    f32x4 r;
    r[0] = fmaxf(a[0], b[0]); r[1] = fmaxf(a[1], b[1]);
    r[2] = fmaxf(a[2], b[2]); r[3] = fmaxf(a[3], b[3]);
    return r;
}

// ---------------- projections (f32 math, exact) ----------------

// Q/K: write bf16, layout [head][n][d] (n-major), optional scale folded in.
__global__ __launch_bounds__(256) void proj_nd_kernel(
    const float* __restrict__ X, const float* __restrict__ W,
    ushort* __restrict__ Y, float scale)
{
    __shared__ float w_lds[8 * NCH];
    const int n  = blockIdx.x * 256 + threadIdx.x;
    const int o0 = blockIdx.y * 8;
    for (int i = threadIdx.x; i < 8 * NCH; i += 256)
        w_lds[i] = W[o0 * NCH + i];
    __syncthreads();

    float acc[8];
#pragma unroll
    for (int j = 0; j < 8; ++j) acc[j] = 0.f;
#pragma unroll 4
    for (int c = 0; c < NCH; ++c) {
        float xv = X[c * NPOS + n];
#pragma unroll
        for (int j = 0; j < 8; ++j)
            acc[j] = fmaf(w_lds[j * NCH + c], xv, acc[j]);
    }
    const int head = o0 >> 5, d0 = o0 & 31;
    ushort* base = Y + head * (NPOS * HD) + n * HD + d0;
#pragma unroll
    for (int j = 0; j < 8; j += 2)
        *(uint*)(base + j) = pk2(acc[j] * scale, acc[j + 1] * scale);
}

// V: write bf16, layout [head*32+d][n] (c-major, same as input).
__global__ __launch_bounds__(256) void proj_dn_bf16_kernel(
    const float* __restrict__ X, const float* __restrict__ W,
    ushort* __restrict__ Y)
{
    __shared__ float w_lds[8 * NCH];
    const int n  = blockIdx.x * 256 + threadIdx.x;
    const int o0 = blockIdx.y * 8;
    for (int i = threadIdx.x; i < 8 * NCH; i += 256)
        w_lds[i] = W[o0 * NCH + i];
    __syncthreads();

    float acc[8];
#pragma unroll
    for (int j = 0; j < 8; ++j) acc[j] = 0.f;
#pragma unroll 4
    for (int c = 0; c < NCH; ++c) {
        float xv = X[c * NPOS + n];
#pragma unroll
        for (int j = 0; j < 8; ++j)
            acc[j] = fmaf(w_lds[j * NCH + c], xv, acc[j]);
    }
#pragma unroll
    for (int j = 0; j < 8; ++j)
        Y[(o0 + j) * NPOS + n] = bfbits(acc[j]);
}

// Output projection: f32 in, f32 out, + bias.
__global__ __launch_bounds__(256) void proj_f32_kernel(
    const float* __restrict__ X, const float* __restrict__ W,
    const float* __restrict__ bias, float* __restrict__ Y)
{
    __shared__ float w_lds[8 * NCH];
    const int n  = blockIdx.x * 256 + threadIdx.x;
    const int o0 = blockIdx.y * 8;
    for (int i = threadIdx.x; i < 8 * NCH; i += 256)
        w_lds[i] = W[o0 * NCH + i];
    __syncthreads();

    float acc[8];
#pragma unroll
    for (int j = 0; j < 8; ++j) acc[j] = 0.f;
#pragma unroll 4
    for (int c = 0; c < NCH; ++c) {
        float xv = X[c * NPOS + n];
#pragma unroll
        for (int j = 0; j < 8; ++j)
            acc[j] = fmaf(w_lds[j * NCH + c], xv, acc[j]);
    }
#pragma unroll
    for (int j = 0; j < 8; ++j)
        Y[(o0 + j) * NPOS + n] = acc[j] + bias[o0 + j];
}

// ---------------- MFMA flash attention ----------------
// grid: 256 blocks (h = bid&7 -> one head per XCD for L2 locality), 4 waves.
// Each wave owns 32 queries. S^T = mfma(Kfrag, Qfrag) so softmax rows are
// m (4 in-lane values per 16-row tile) -> reduce = in-lane + shfl_xor(16,32).
// P goes through per-wave swizzled LDS; K/V fragments come straight from L2.
__global__ __launch_bounds__(256) void attn_mfma_kernel(
    const ushort* __restrict__ Qt,   // [8][4096][32] bf16, pre-scaled by s*log2e
    const ushort* __restrict__ Kt,   // [8][4096][32] bf16
    const ushort* __restrict__ Vt,   // [8][32][4096] bf16
    float* __restrict__ F)           // [256][4096] f32
{
    __shared__ ushort pt_all[4][32 * KB];
    const int bid  = blockIdx.x;
    const int h    = bid & 7;
    const int qblk = bid >> 3;
    const int wid  = threadIdx.x >> 6;
    const int lane = threadIdx.x & 63;
    const int lq   = lane & 15;     // fragment column (query)
    const int grp  = lane >> 4;     // 0..3
    const int q0   = qblk * 128 + wid * 32;

    ushort* pt = pt_all[wid];
    const int hq = h * (NPOS * HD);

    // Q B-fragments, held in registers for the whole K loop
    s16x8 qf[2];
#pragma unroll
    for (int qt = 0; qt < 2; ++qt)
        qf[qt] = load8(Qt + hq + (q0 + qt * 16 + lq) * HD + grp * 8);

    const ushort* kbase = Kt + hq + lq * HD + grp * 8;
    const ushort* vbase = Vt + h * (HD * NPOS) + lq * NPOS + grp * 8;

    f32x4 oacc[2][2];
#pragma unroll
    for (int qt = 0; qt < 2; ++qt)
#pragma unroll
        for (int dt = 0; dt < 2; ++dt)
            oacc[qt][dt] = (f32x4){0.f, 0.f, 0.f, 0.f};
    float m_run[2] = {-INFINITY, -INFINITY};
    float l_run[2] = {0.f, 0.f};

    s16x8 kf[4];
#pragma unroll
    for (int t = 0; t < 4; ++t) kf[t] = load8(kbase + t * 16 * HD);

    for (int m0 = 0; m0 < NPOS; m0 += KB) {
        // --- QK^T: S^T tiles (rows = m, cols = q) ---
        f32x4 s[2][4];
#pragma unroll
        for (int t = 0; t < 4; ++t)
#pragma unroll
            for (int qt = 0; qt < 2; ++qt)
                s[qt][t] = __builtin_amdgcn_mfma_f32_16x16x32_bf16(
                    kf[t], qf[qt], (f32x4){0.f, 0.f, 0.f, 0.f}, 0, 0, 0);

        // prefetch next K tile + this step's V fragments (hide L2 latency
        // under the softmax VALU work)
        const int mn = (m0 + KB) & (NPOS - 1);
        s16x8 kn[4];
#pragma unroll
        for (int t = 0; t < 4; ++t) kn[t] = load8(kbase + (mn + t * 16) * HD);
        s16x8 vf[2][2];
#pragma unroll
        for (int ks = 0; ks < 2; ++ks)
#pragma unroll
            for (int dt = 0; dt < 2; ++dt)
                vf[ks][dt] = load8(vbase + dt * 16 * NPOS + m0 + ks * 32);

        // --- online softmax (exp2 domain; Q pre-scaled by s*log2e) ---
#pragma unroll
        for (int qt = 0; qt < 2; ++qt) {
            f32x4 mv = max4(max4(s[qt][0], s[qt][1]), max4(s[qt][2], s[qt][3]));
            float mt = fmaxf(fmaxf(mv[0], mv[1]), fmaxf(mv[2], mv[3]));
            mt = fmaxf(mt, __shfl_xor(mt, 16));
            mt = fmaxf(mt, __shfl_xor(mt, 32));
            const float mnew  = fmaxf(m_run[qt], mt);
            const float alpha = __builtin_amdgcn_exp2f(m_run[qt] - mnew);
            m_run[qt] = mnew;
            l_run[qt] *= alpha;
            oacc[qt][0] *= alpha;
            oacc[qt][1] *= alpha;
            float ls = 0.f;
#pragma unroll
            for (int t = 0; t < 4; ++t) {
                const float p0 = __builtin_amdgcn_exp2f(s[qt][t][0] - mnew);
                const float p1 = __builtin_amdgcn_exp2f(s[qt][t][1] - mnew);
                const float p2 = __builtin_amdgcn_exp2f(s[qt][t][2] - mnew);
                const float p3 = __builtin_amdgcn_exp2f(s[qt][t][3] - mnew);
                ls += (p0 + p1) + (p2 + p3);
                const int mrow = t * 16 + grp * 4;
                const int hw = (qt * 16 + lq) * KB +
                               (((mrow >> 3) ^ (lq & 7)) << 3) + (mrow & 7);
                *(uint*)(pt + hw)     = pk2(p0, p1);
                *(uint*)(pt + hw + 2) = pk2(p2, p3);
            }
            l_run[qt] += ls;
        }

        // --- PV: O^T (rows = d, cols = q), contract over m ---
#pragma unroll
        for (int ks = 0; ks < 2; ++ks)
#pragma unroll
            for (int qt = 0; qt < 2; ++qt) {
                const int hw = (qt * 16 + lq) * KB +
                               ((((ks * 32 + grp * 8) >> 3) ^ (lq & 7)) << 3);
                const s16x8 pf = *(const s16x8*)(pt + hw);
                oacc[qt][0] = __builtin_amdgcn_mfma_f32_16x16x32_bf16(
                    vf[ks][0], pf, oacc[qt][0], 0, 0, 0);
                oacc[qt][1] = __builtin_amdgcn_mfma_f32_16x16x32_bf16(
                    vf[ks][1], pf, oacc[qt][1], 0, 0, 0);
            }

#pragma unroll
        for (int t = 0; t < 4; ++t) kf[t] = kn[t];
    }

    // --- normalize + write fused (f32, [c][n]) ---
#pragma unroll
    for (int qt = 0; qt < 2; ++qt) {
        float l = l_run[qt];
        l += __shfl_xor(l, 16);
        l += __shfl_xor(l, 32);
        const float inv = 1.f / l;
        const int n = q0 + qt * 16 + lq;
#pragma unroll
        for (int dt = 0; dt < 2; ++dt)
#pragma unroll
            for (int r = 0; r < 4; ++r)
                F[(h * HD + dt * 16 + grp * 4 + r) * NPOS + n] =
                    oacc[qt][dt][r] * inv;
    }
}

extern "C" void kernel_launch(void* const* d_in, const int* in_sizes, int n_in,
                              void* d_out, int out_size, void* d_ws, size_t ws_size,
                              hipStream_t stream) {
    const float* x1 = (const float*)d_in[0];
    const float* x2 = (const float*)d_in[1];
    const float* Wq = (const float*)d_in[2];
    const float* Wk = (const float*)d_in[3];
    const float* Wv = (const float*)d_in[4];
    const float* Wp = (const float*)d_in[5];
    const float* bp = (const float*)d_in[6];
    float* out = (float*)d_out;

    ushort* qt = (ushort*)d_ws;              // 2 MB bf16 [8][4096][32]
    ushort* kt = qt + NPOS * NCH;            // 2 MB
    ushort* vt = kt + NPOS * NCH;            // 2 MB [8][32][4096]
    float*  fu = (float*)(vt + NPOS * NCH);  // 4 MB f32 [256][4096]

    const float qscale = (float)(0.17677669529663687 * 1.4426950408889634);

    dim3 pgrid(NPOS / 256, NCH / 8);
    proj_nd_kernel<<<pgrid, 256, 0, stream>>>(x1, Wq, qt, qscale);
    proj_nd_kernel<<<pgrid, 256, 0, stream>>>(x2, Wk, kt, 1.0f);
    proj_dn_bf16_kernel<<<pgrid, 256, 0, stream>>>(x2, Wv, vt);

    attn_mfma_kernel<<<256, 256, 0, stream>>>(qt, kt, vt, fu);

    proj_f32_kernel<<<pgrid, 256, 0, stream>>>(fu, Wp, bp, out);
}